// Round 6
// baseline (244.946 us; speedup 1.0000x reference)
//
#include <hip/hip_runtime.h>

#define DIN 256
#define NTOK 4096

typedef __bf16 bf16;
typedef __bf16 bf16x4 __attribute__((ext_vector_type(4)));
typedef __bf16 bf16x8 __attribute__((ext_vector_type(8)));
typedef float floatx16 __attribute__((ext_vector_type(16)));

__device__ inline floatx16 mfma32(bf16x8 a, bf16x8 b, floatx16 c) {
    return __builtin_amdgcn_mfma_f32_32x32x16_bf16(a, b, c, 0, 0, 0);
}

// async global->LDS, 16B per lane. g: per-lane global addr; l: wave-uniform LDS base.
__device__ inline void async16(const void* g, void* l) {
    __builtin_amdgcn_global_load_lds(
        (const __attribute__((address_space(1))) unsigned int*)g,
        (__attribute__((address_space(3))) unsigned int*)l, 16, 0, 0);
}

// ---------------- kernel 1: cast weights to bf16 ----------------
__global__ void convert_w(const float* __restrict__ wq, const float* __restrict__ wk,
                          const float* __restrict__ wv, bf16* __restrict__ Wb) {
    int i = blockIdx.x * 256 + threadIdx.x;   // 0..196607
    const float* src = (i < 65536) ? wq : (i < 131072 ? wk : wv);
    Wb[i] = (bf16)src[i & 65535];
}

// ---------------- kernel 2: QKV projection v3b (unchanged) ----------------
__global__ __launch_bounds__(512, 2) void proj_kernel(
    const float* __restrict__ x, const bf16* __restrict__ Wb,
    bf16* __restrict__ Qo, bf16* __restrict__ Ko, bf16* __restrict__ Vo)
{
    __shared__ __attribute__((aligned(16))) char smem[131072];
    bf16 (*xs)[264] = (bf16(*)[264])smem;
    bf16* bufA = (bf16*)smem;
    bf16* bufB = (bf16*)(smem + 65536);

    int bid = blockIdx.x;
    int b = bid & 7, nt = bid >> 3;
    int n0 = nt * 128;
    int t = threadIdx.x;
    int lane = t & 63, w = t >> 6;
    int l32 = lane & 31, h = lane >> 5;
    int tokg = w >> 1;
    int og   = w & 1;

    int wofs[8];
#pragma unroll
    for (int jj = 0; jj < 8; ++jj) {
        int q = w * 8 + jj;
        int r2 = 2 * q + h;
        int cs = l32 ^ (r2 & 31);
        wofs[jj] = r2 * 512 + cs * 16;
    }

    {
        const float* xb = x + (size_t)b * DIN * NTOK;
#pragma unroll
        for (int it = 0; it < 16; ++it) {
            int flat = it * 512 + t;
            int c = flat >> 5;
            int nf = flat & 31;
            float4 v = *(const float4*)(xb + (size_t)c * NTOK + n0 + nf * 4);
            int nn = nf * 4;
            xs[nn + 0][c] = (bf16)v.x;
            xs[nn + 1][c] = (bf16)v.y;
            xs[nn + 2][c] = (bf16)v.z;
            xs[nn + 3][c] = (bf16)v.w;
        }
    }
    __syncthreads();

    bf16x8 xf[16];
#pragma unroll
    for (int ks = 0; ks < 16; ++ks)
        xf[ks] = *(const bf16x8*)&xs[tokg * 32 + l32][ks * 16 + h * 8];

    __syncthreads();

    {
        const char* src = (const char*)Wb;
#pragma unroll
        for (int jj = 0; jj < 8; ++jj)
            async16(src + wofs[jj], (char*)bufA + (w * 8 + jj) * 1024);
    }
    __syncthreads();

    for (int p = 0; p < 6; ++p) {
        if (p < 5) {
            bf16* nb = ((p + 1) & 1) ? bufB : bufA;
            const char* src = (const char*)Wb + (size_t)(p + 1) * 65536;
#pragma unroll
            for (int jj = 0; jj < 8; ++jj)
                async16(src + wofs[jj], (char*)nb + (w * 8 + jj) * 1024);
        }

        const bf16* wb = (p & 1) ? bufB : bufA;
        int mat = p >> 1, dhalf = p & 1;

        floatx16 acc[2];
#pragma unroll
        for (int dc = 0; dc < 2; ++dc)
#pragma unroll
            for (int i = 0; i < 16; ++i) acc[dc][i] = 0.0f;

        if (mat < 2) {
#pragma unroll
            for (int ks = 0; ks < 16; ++ks) {
#pragma unroll
                for (int dc = 0; dc < 2; ++dc) {
                    int row = og * 64 + dc * 32 + l32;
                    bf16x8 wf = *(const bf16x8*)((const char*)wb + row * 512 +
                                                 (((2 * ks + h) ^ (row & 31)) * 16));
                    acc[dc] = mfma32(xf[ks], wf, acc[dc]);
                }
            }
            bf16* Out = (mat == 0 ? Qo : Ko) + (size_t)b * NTOK * DIN;
#pragma unroll
            for (int dc = 0; dc < 2; ++dc) {
                int d = dhalf * 128 + og * 64 + dc * 32 + l32;
#pragma unroll
                for (int r = 0; r < 16; ++r) {
                    int tok = n0 + tokg * 32 + (r & 3) + 8 * (r >> 2) + 4 * h;
                    Out[(size_t)tok * DIN + d] = (bf16)acc[dc][r];
                }
            }
        } else {
#pragma unroll
            for (int ks = 0; ks < 16; ++ks) {
#pragma unroll
                for (int dc = 0; dc < 2; ++dc) {
                    int row = og * 64 + dc * 32 + l32;
                    bf16x8 wf = *(const bf16x8*)((const char*)wb + row * 512 +
                                                 (((2 * ks + h) ^ (row & 31)) * 16));
                    acc[dc] = mfma32(wf, xf[ks], acc[dc]);
                }
            }
            bf16* Out = Vo + (size_t)b * DIN * NTOK;
            int tok = n0 + tokg * 32 + l32;
#pragma unroll
            for (int dc = 0; dc < 2; ++dc)
#pragma unroll
                for (int r = 0; r < 16; ++r) {
                    int d = dhalf * 128 + og * 64 + dc * 32 + (r & 3) + 8 * (r >> 2) + 4 * h;
                    Out[(size_t)d * NTOK + tok] = (bf16)acc[dc][r];
                }
        }
        __syncthreads();
    }
}

// ---------------- kernel 3: attention v5 — 12 waves, halved per-wave tiles ----------------
// R5 post-mortem: dur/MfmaUtil/Occupancy invariant across LDS-traffic cut (R3) and
// counted-vmcnt (R5) -> latency-bound at 2 waves/SIMD; no pipe >40% of the wall.
// v5 raises occupancy to 3 waves/SIMD the VGPR-feasible way (R1 lesson: halve
// per-wave state, don't squeeze): 4 producers each own 32q x full kv64 (qf=64
// VGPR, was 128); 8 consumers each own 64d x 64q (oacc=64 VGPR, was 128).
// Same MFMA totals, same proven R2 dbuf/barrier skeleton, same swizzle (key
// invariant under +32-row offsets). Per SIMD: 1 producer + 2 consumers -> exp
// phase overlaps two MFMA-heavy waves. LDS 160KB. launch_bounds(768,3) caps
// VGPR ~168. Tripwire: WRITE_SIZE must stay 32768 KB (jump = spill).
__global__ __launch_bounds__(768, 3) void attn_kernel(
    const bf16* __restrict__ Q, const bf16* __restrict__ K,
    const bf16* __restrict__ V, float* __restrict__ out)
{
    __shared__ bf16 Ks[2][64][256];   // 64 KB
    __shared__ bf16 Vs[2][256][64];   // 64 KB
    __shared__ bf16 Ps[2][128][64];   // 32 KB  (160 KB total)

    int bid = blockIdx.x;
    int b = bid & 7, qt = bid >> 3;   // batch -> XCD L2 locality
    int n0 = qt * 128;
    int t = threadIdx.x, lane = t & 63, w = t >> 6;   // 12 waves
    int l32 = lane & 31, h = lane >> 5;
    int lkey = (l32 & 7) ^ ((l32 >> 3) & 3);   // swizzle key (row-offset invariant)

    const bf16* Qb = Q + (size_t)b * NTOK * DIN;
    const bf16* Kb = K + (size_t)b * NTOK * DIN;
    const bf16* Vb = V + (size_t)b * DIN * NTOK;
    float* Lp = (float*)&Ps[0][0][0];   // 128 floats, reused AFTER last barrier

    if (w < 4) {
        // ===== S-producer: wave qg owns q-rows qg*32..+31, full kv 0..63 =====
        int qg = w;

        int koff[8];
#pragma unroll
        for (int jj = 0; jj < 8; ++jj) {
            int q = w * 8 + jj;
            int r = q * 2 + h;
            int ck = l32 ^ ((r & 7) ^ ((r >> 3) & 3));
            koff[jj] = (r * 256 + ck * 8) * 2;
        }

        bf16x8 qf[16];
        {
            const bf16* qrow = Qb + (size_t)(n0 + qg * 32 + l32) * DIN + h * 8;
#pragma unroll
            for (int ks = 0; ks < 16; ++ks) qf[ks] = *(const bf16x8*)(qrow + ks * 16);
        }

        float lsum = 0.0f;

        // prologue: K(0)->buf0, K(1)->buf1
#pragma unroll
        for (int jj = 0; jj < 8; ++jj) {
            async16((const char*)Kb + koff[jj], (bf16*)Ks[0] + (w * 8 + jj) * 512);
            async16((const char*)Kb + 32768 + koff[jj], (bf16*)Ks[1] + (w * 8 + jj) * 512);
        }
        __syncthreads();   // (1)

        // compute P0 -> Ps[0]
        {
            const bf16* Krd = (const bf16*)Ks[0] + l32 * 256;
            floatx16 st0, st1;
#pragma unroll
            for (int i = 0; i < 16; ++i) { st0[i] = 0.0f; st1[i] = 0.0f; }
#pragma unroll
            for (int ks = 0; ks < 16; ++ks) {
                int co = ((2 * ks + h) ^ lkey) * 8;
                bf16x8 kf0 = *(const bf16x8*)(Krd + co);
                bf16x8 kf1 = *(const bf16x8*)(Krd + 32 * 256 + co);
                st0 = mfma32(kf0, qf[ks], st0);
                st1 = mfma32(kf1, qf[ks], st1);
            }
            bf16* Prow = (bf16*)Ps[0] + (qg * 32 + l32) * 64;
#pragma unroll
            for (int kvb = 0; kvb < 2; ++kvb) {
#pragma unroll
                for (int g = 0; g < 4; ++g) {
                    bf16x4 pk;
#pragma unroll
                    for (int i = 0; i < 4; ++i) {
                        float sval = kvb ? st1[g * 4 + i] : st0[g * 4 + i];
                        float e = __expf(sval * 0.0625f);
                        lsum += e;
                        pk[i] = (bf16)e;
                    }
                    *(bf16x4*)((char*)Prow + (((kvb * 4 + g) ^ lkey) * 16) + h * 8) = pk;
                }
            }
        }
        __syncthreads();   // (2)

#pragma unroll 1
        for (int mt = 0; mt < 64; ++mt) {
            if (mt < 62) {   // DMA K(mt+2) -> Ks[mt&1]
                int kadd = (mt + 2) * 32768;
#pragma unroll
                for (int jj = 0; jj < 8; ++jj)
                    async16((const char*)Kb + kadd + koff[jj],
                            (bf16*)Ks[mt & 1] + (w * 8 + jj) * 512);
            }
            if (mt < 63) {   // compute P(mt+1): Ks[(mt+1)&1] -> Ps[(mt+1)&1]
                const bf16* Krd = (const bf16*)Ks[(mt + 1) & 1] + l32 * 256;
                floatx16 st0, st1;
#pragma unroll
                for (int i = 0; i < 16; ++i) { st0[i] = 0.0f; st1[i] = 0.0f; }
#pragma unroll
                for (int ks = 0; ks < 16; ++ks) {
                    int co = ((2 * ks + h) ^ lkey) * 8;
                    bf16x8 kf0 = *(const bf16x8*)(Krd + co);
                    bf16x8 kf1 = *(const bf16x8*)(Krd + 32 * 256 + co);
                    st0 = mfma32(kf0, qf[ks], st0);
                    st1 = mfma32(kf1, qf[ks], st1);
                }
                bf16* Prow = (bf16*)Ps[(mt + 1) & 1] + (qg * 32 + l32) * 64;
#pragma unroll
                for (int kvb = 0; kvb < 2; ++kvb) {
#pragma unroll
                    for (int g = 0; g < 4; ++g) {
                        bf16x4 pk;
#pragma unroll
                        for (int i = 0; i < 4; ++i) {
                            float sval = kvb ? st1[g * 4 + i] : st0[g * 4 + i];
                            float e = __expf(sval * 0.0625f);
                            lsum += e;
                            pk[i] = (bf16)e;
                        }
                        *(bf16x4*)((char*)Prow + (((kvb * 4 + g) ^ lkey) * 16) + h * 8) = pk;
                    }
                }
            }
            __syncthreads();   // single barrier per iter
        }

        // epilogue: h-pair reduce, publish row sums (Ps now dead -> Lp alias ok)
        {
            float sv = lsum;
            sv += __shfl_xor(sv, 32);
            if (h == 0) Lp[qg * 32 + l32] = sv;
        }
        __syncthreads();   // (3)
    } else {
        // ===== PV-consumer: wave (slab2,qh) owns O^T[64d][64q] =====
        int ws = w - 4;            // 0..7
        int slab2 = ws >> 1;       // d 64-block
        int qh = ws & 1;           // q 64-half

        int vofs[4];
#pragma unroll
        for (int jj = 0; jj < 4; ++jj) {
            int q = ws * 4 + jj;
            int d = q * 8 + (lane >> 3);
            int cv = (lane & 7) ^ ((d & 7) ^ ((d >> 3) & 3));
            vofs[jj] = (d * 4096 + cv * 8) * 2;
        }

        floatx16 oacc[4];   // [dc*2+tc]
#pragma unroll
        for (int i = 0; i < 4; ++i)
            for (int j = 0; j < 16; ++j) oacc[i][j] = 0.0f;

        // prologue: V(0)->buf0
#pragma unroll
        for (int jj = 0; jj < 4; ++jj)
            async16((const char*)Vb + vofs[jj], (bf16*)Vs[0] + (ws * 4 + jj) * 512);
        __syncthreads();   // (1)
        __syncthreads();   // (2)

#pragma unroll 1
        for (int mt = 0; mt < 64; ++mt) {
            if (mt < 63) {   // DMA V(mt+1) -> Vs[(mt+1)&1]
                int vadd = (mt + 1) * 128;
#pragma unroll
                for (int jj = 0; jj < 4; ++jj)
                    async16((const char*)Vb + vadd + vofs[jj],
                            (bf16*)Vs[(mt + 1) & 1] + (ws * 4 + jj) * 512);
            }
            const bf16* Vrd = (const bf16*)Vs[mt & 1];
            const char* Prd = (const char*)Ps[mt & 1];
#pragma unroll
            for (int kst = 0; kst < 4; ++kst) {
                int co = ((kst * 2 + h) ^ lkey);
                int d0 = slab2 * 64 + l32;
                bf16x8 va0 = *(const bf16x8*)(Vrd + d0 * 64 + co * 8);
                bf16x8 va1 = *(const bf16x8*)(Vrd + (d0 + 32) * 64 + co * 8);
                bf16x8 pb0 = *(const bf16x8*)(Prd + (qh * 64 + l32) * 128 + co * 16);
                bf16x8 pb1 = *(const bf16x8*)(Prd + (qh * 64 + 32 + l32) * 128 + co * 16);
                oacc[0] = mfma32(va0, pb0, oacc[0]);
                oacc[1] = mfma32(va0, pb1, oacc[1]);
                oacc[2] = mfma32(va1, pb0, oacc[2]);
                oacc[3] = mfma32(va1, pb1, oacc[3]);
            }
            __syncthreads();   // single barrier per iter
        }

        __syncthreads();   // (3): Lp ready
        float* ob = out + (size_t)b * DIN * NTOK;
#pragma unroll
        for (int tc = 0; tc < 2; ++tc) {
            int tokl = qh * 64 + tc * 32 + l32;
            float rinv = 1.0f / Lp[tokl];
#pragma unroll
            for (int dc = 0; dc < 2; ++dc)
#pragma unroll
                for (int r = 0; r < 16; ++r) {
                    int d = slab2 * 64 + dc * 32 + (r & 3) + 8 * (r >> 2) + 4 * h;
                    ob[(size_t)d * NTOK + n0 + tokl] = oacc[dc * 2 + tc][r] * rinv;
                }
        }
    }
}

// ---------------- launcher ----------------
extern "C" void kernel_launch(void* const* d_in, const int* in_sizes, int n_in,
                              void* d_out, int out_size, void* d_ws, size_t ws_size,
                              hipStream_t stream) {
    const float* x  = (const float*)d_in[0];
    const float* wq = (const float*)d_in[1];
    const float* wk = (const float*)d_in[2];
    const float* wv = (const float*)d_in[3];
    float* outf = (float*)d_out;

    char* ws = (char*)d_ws;
    bf16* Wb = (bf16*)(ws);                                  // 384 KB
    bf16* Qp = (bf16*)(ws + (1u << 20));                     // 16 MB
    bf16* Kp = (bf16*)(ws + (1u << 20) + (16u << 20));       // 16 MB
    bf16* Vp = (bf16*)(ws + (1u << 20) + (32u << 20));       // 16 MB

    convert_w<<<768, 256, 0, stream>>>(wq, wk, wv, Wb);
    proj_kernel<<<256, 512, 0, stream>>>(x, Wb, Qp, Kp, Vp);
    attn_kernel<<<256, 768, 0, stream>>>(Qp, Kp, Vp, outf);
}